// Round 1
// baseline (329.771 us; speedup 1.0000x reference)
//
#include <hip/hip_runtime.h>

#define NNODES 50000
#define NEDGES 800000
#define DIN 128
#define DHID 128
#define DOUT 64
#define CAP 96

// ---------------------------------------------------------------------------
// Pass 1: per-edge degree count + bucket fill (CSR-free grouping by dst).
// bucket[d*CAP + p] = src for the p-th in-edge of node d.
// ---------------------------------------------------------------------------
__global__ __launch_bounds__(256) void count_fill_kernel(
    const int* __restrict__ src, const int* __restrict__ dst,
    int* __restrict__ deg, int* __restrict__ bucket, int E) {
  int e = blockIdx.x * 256 + threadIdx.x;
  if (e >= E) return;
  int d = dst[e];
  int s = src[e];
  int p = atomicAdd(&deg[d], 1);
  if (p < CAP) bucket[(size_t)d * CAP + p] = s;
}

// ---------------------------------------------------------------------------
// Pass 2: dinv[i] = rsqrt(deg[i] + 1)   (self-loop included in degree)
// ---------------------------------------------------------------------------
__global__ __launch_bounds__(256) void dinv_kernel(
    const int* __restrict__ deg, float* __restrict__ dinv, int n) {
  int i = blockIdx.x * 256 + threadIdx.x;
  if (i < n) dinv[i] = rsqrtf((float)deg[i] + 1.0f);
}

// ---------------------------------------------------------------------------
// FP32 GEMM  C[M,NCOL] = A[M,128] * W[128,NCOL].  BM=64, BN=64, BK=16.
// 256 threads, 4x4 micro-tile per thread.
// ---------------------------------------------------------------------------
template <int NCOL>
__global__ __launch_bounds__(256) void gemm_k128_kernel(
    const float* __restrict__ A, const float* __restrict__ W,
    float* __restrict__ C, int M) {
  constexpr int BK = 16;
  constexpr int PAD = 68;  // 68*4B = 272B stride, keeps float4 LDS reads 16B-aligned
  __shared__ float As[BK][PAD];  // [k][row]
  __shared__ float Ws[BK][PAD];  // [k][col]

  const int tid = threadIdx.x;
  const int tc = tid & 15;   // 0..15 -> col group
  const int tr = tid >> 4;   // 0..15 -> row group
  const int m0 = blockIdx.x * 64;
  const int n0 = (NCOL > 64) ? (blockIdx.y * 64) : 0;

  // A staging: thread loads float4 at (row = tid>>2, k = (tid&3)*4)
  const int arow = tid >> 2;
  const int akq = (tid & 3) * 4;
  const int grow = m0 + arow;
  // W staging: thread loads float4 at (k = tid>>4, col = (tid&15)*4)
  const int wk = tid >> 4;
  const int wc = (tid & 15) * 4;

  float acc[4][4] = {};

  for (int k0 = 0; k0 < 128; k0 += BK) {
    float4 av = make_float4(0.f, 0.f, 0.f, 0.f);
    if (grow < M) av = *(const float4*)(A + (size_t)grow * 128 + k0 + akq);
    float4 wv = *(const float4*)(W + (size_t)(k0 + wk) * NCOL + n0 + wc);
    __syncthreads();  // previous-iteration LDS reads complete
    As[akq + 0][arow] = av.x;
    As[akq + 1][arow] = av.y;
    As[akq + 2][arow] = av.z;
    As[akq + 3][arow] = av.w;
    *(float4*)&Ws[wk][wc] = wv;
    __syncthreads();
#pragma unroll
    for (int k = 0; k < BK; ++k) {
      float4 a4 = *(const float4*)&As[k][tr * 4];
      float4 b4 = *(const float4*)&Ws[k][tc * 4];
      float a[4] = {a4.x, a4.y, a4.z, a4.w};
      float b[4] = {b4.x, b4.y, b4.z, b4.w};
#pragma unroll
      for (int i = 0; i < 4; ++i)
#pragma unroll
        for (int j = 0; j < 4; ++j) acc[i][j] += a[i] * b[j];
    }
  }

#pragma unroll
  for (int i = 0; i < 4; ++i) {
    int r = m0 + tr * 4 + i;
    if (r < M) {
      *(float4*)(C + (size_t)r * NCOL + n0 + tc * 4) =
          make_float4(acc[i][0], acc[i][1], acc[i][2], acc[i][3]);
    }
  }
}

// ---------------------------------------------------------------------------
// Aggregation: one wave (64 lanes) per node. COLS=128 -> float2/lane,
// COLS=64 -> float/lane.  out = relu(sum_{e in-edges} h[src]*dinv[s]*dinv[d]
//                                    + h[d]*dinv[d]^2 + bias)
// ---------------------------------------------------------------------------
template <int COLS>
__global__ __launch_bounds__(256) void aggregate_kernel(
    const float* __restrict__ h, const int* __restrict__ bucket,
    const int* __restrict__ deg, const float* __restrict__ dinv,
    const float* __restrict__ bias, float* __restrict__ out, int n) {
  const int wave = threadIdx.x >> 6;
  const int lane = threadIdx.x & 63;
  const int nid = blockIdx.x * 4 + wave;
  if (nid >= n) return;

  const float di = dinv[nid];
  int d = deg[nid];
  if (d > CAP) d = CAP;
  const int* bkt = bucket + (size_t)nid * CAP;

  if (COLS == 128) {
    float2 acc = {0.f, 0.f};
    for (int p = 0; p < d; ++p) {
      int s = bkt[p];
      float w = di * dinv[s];
      float2 hv = *(const float2*)(h + (size_t)s * 128 + lane * 2);
      acc.x += hv.x * w;
      acc.y += hv.y * w;
    }
    float w2 = di * di;
    float2 hv = *(const float2*)(h + (size_t)nid * 128 + lane * 2);
    acc.x += hv.x * w2;
    acc.y += hv.y * w2;
    float2 bv = *(const float2*)(bias + lane * 2);
    acc.x = fmaxf(acc.x + bv.x, 0.f);
    acc.y = fmaxf(acc.y + bv.y, 0.f);
    *(float2*)(out + (size_t)nid * 128 + lane * 2) = acc;
  } else {
    float acc = 0.f;
    for (int p = 0; p < d; ++p) {
      int s = bkt[p];
      float w = di * dinv[s];
      acc += h[(size_t)s * 64 + lane] * w;
    }
    acc += h[(size_t)nid * 64 + lane] * di * di;
    acc = fmaxf(acc + bias[lane], 0.f);
    out[(size_t)nid * 64 + lane] = acc;
  }
}

// ---------------------------------------------------------------------------
extern "C" void kernel_launch(void* const* d_in, const int* in_sizes, int n_in,
                              void* d_out, int out_size, void* d_ws, size_t ws_size,
                              hipStream_t stream) {
  const float* x = (const float*)d_in[0];
  const int* edge = (const int*)d_in[1];
  const float* W1 = (const float*)d_in[2];
  const float* b1 = (const float*)d_in[3];
  const float* W2 = (const float*)d_in[4];
  const float* b2 = (const float*)d_in[5];
  float* out = (float*)d_out;

  const int N = in_sizes[0] / DIN;     // 50000
  const int E = in_sizes[1] / 2;       // 800000
  const int* src = edge;
  const int* dst = edge + E;

  // workspace carve-up (256B aligned)
  char* base = (char*)d_ws;
  size_t off = 0;
  auto carve = [&](size_t bytes) {
    char* p = base + off;
    off += (bytes + 255) & ~(size_t)255;
    return p;
  };
  int* deg = (int*)carve((size_t)N * 4);
  float* dinv = (float*)carve((size_t)N * 4);
  int* bucket = (int*)carve((size_t)N * CAP * 4);
  float* h1 = (float*)carve((size_t)N * DHID * 4);   // also reused as h2t [N,64]
  float* hb = (float*)carve((size_t)N * DHID * 4);
  float* h2t = h1;  // alias: h1 dead after aggregate1

  hipMemsetAsync(deg, 0, (size_t)N * 4, stream);

  count_fill_kernel<<<(E + 255) / 256, 256, 0, stream>>>(src, dst, deg, bucket, E);
  dinv_kernel<<<(N + 255) / 256, 256, 0, stream>>>(deg, dinv, N);

  // layer 1: h1 = x @ W1 ; hb = relu(agg(h1) + b1)
  {
    dim3 grid((N + 63) / 64, 2);
    gemm_k128_kernel<DHID><<<grid, 256, 0, stream>>>(x, W1, h1, N);
  }
  aggregate_kernel<DHID><<<(N + 3) / 4, 256, 0, stream>>>(h1, bucket, deg, dinv, b1, hb, N);

  // layer 2: h2t = hb @ W2 ; out = relu(agg(h2t) + b2)
  {
    dim3 grid((N + 63) / 64, 1);
    gemm_k128_kernel<DOUT><<<grid, 256, 0, stream>>>(hb, W2, h2t, N);
  }
  aggregate_kernel<DOUT><<<(N + 3) / 4, 256, 0, stream>>>(h2t, bucket, deg, dinv, b2, out, N);
}

// Round 2
// 247.521 us; speedup vs baseline: 1.3323x; 1.3323x over previous
//
#include <hip/hip_runtime.h>

#define NNODES 50000
#define NEDGES 800000
#define DIN 128
#define DHID 128
#define DOUT 64
#define CAP 96

// ---- bf16 helpers (manual, no header-API dependence) ----------------------
static __device__ __forceinline__ unsigned short f2bf(float f) {
  union { float f; unsigned u; } v; v.f = f;
  unsigned r = v.u + 0x7fffu + ((v.u >> 16) & 1u);  // round-nearest-even
  return (unsigned short)(r >> 16);
}
static __device__ __forceinline__ float bf_lo(unsigned v) {  // low 16 bits -> float
  union { unsigned u; float f; } t; t.u = v << 16; return t.f;
}
static __device__ __forceinline__ float bf_hi(unsigned v) {  // high 16 bits -> float
  union { unsigned u; float f; } t; t.u = v & 0xffff0000u; return t.f;
}
static __device__ __forceinline__ float bf1(unsigned short v) {
  union { unsigned u; float f; } t; t.u = ((unsigned)v) << 16; return t.f;
}

// ---------------------------------------------------------------------------
// Pass 1: per-edge degree count + bucket fill (CSR-free grouping by dst).
// ---------------------------------------------------------------------------
__global__ __launch_bounds__(256) void count_fill_kernel(
    const int* __restrict__ src, const int* __restrict__ dst,
    int* __restrict__ deg, int* __restrict__ bucket, int E) {
  int e = blockIdx.x * 256 + threadIdx.x;
  if (e >= E) return;
  int d = dst[e];
  int s = src[e];
  int p = atomicAdd(&deg[d], 1);
  if (p < CAP) bucket[(size_t)d * CAP + p] = s;
}

// ---------------------------------------------------------------------------
// Pass 2: dinv[i] = rsqrt(deg[i] + 1)
// ---------------------------------------------------------------------------
__global__ __launch_bounds__(256) void dinv_kernel(
    const int* __restrict__ deg, float* __restrict__ dinv, int n) {
  int i = blockIdx.x * 256 + threadIdx.x;
  if (i < n) dinv[i] = rsqrtf((float)deg[i] + 1.0f);
}

// ---------------------------------------------------------------------------
// Pass 3: per-slot edge weight  wbkt[i*CAP+p] = dinv[bucket[i*CAP+p]]*dinv[i]
// Reused by BOTH aggregate layers -> dinv gather paid once.
// ---------------------------------------------------------------------------
__global__ __launch_bounds__(256) void weight_fill_kernel(
    const int* __restrict__ bucket, const int* __restrict__ deg,
    const float* __restrict__ dinv, float* __restrict__ wbkt, int total) {
  int idx = blockIdx.x * 256 + threadIdx.x;
  if (idx >= total) return;
  int node = idx / CAP;
  int p = idx - node * CAP;
  int dd = deg[node];
  if (dd > CAP) dd = CAP;
  if (p < dd) wbkt[idx] = dinv[bucket[idx]] * dinv[node];
}

// ---------------------------------------------------------------------------
// FP32 GEMM  C[M,NCOL] = A[M,128] * W[128,NCOL], bf16 output.
// BM=64, BN=64, BK=16, 256 threads, 4x4 micro-tile.
// ---------------------------------------------------------------------------
template <int NCOL>
__global__ __launch_bounds__(256) void gemm_k128_kernel(
    const float* __restrict__ A, const float* __restrict__ W,
    unsigned short* __restrict__ C, int M) {
  constexpr int BK = 16;
  constexpr int PAD = 68;
  __shared__ float As[BK][PAD];  // [k][row]
  __shared__ float Ws[BK][PAD];  // [k][col]

  const int tid = threadIdx.x;
  const int tc = tid & 15;
  const int tr = tid >> 4;
  const int m0 = blockIdx.x * 64;
  const int n0 = (NCOL > 64) ? (blockIdx.y * 64) : 0;

  const int arow = tid >> 2;
  const int akq = (tid & 3) * 4;
  const int grow = m0 + arow;
  const int wk = tid >> 4;
  const int wc = (tid & 15) * 4;

  float acc[4][4] = {};

  for (int k0 = 0; k0 < 128; k0 += BK) {
    float4 av = make_float4(0.f, 0.f, 0.f, 0.f);
    if (grow < M) av = *(const float4*)(A + (size_t)grow * 128 + k0 + akq);
    float4 wv = *(const float4*)(W + (size_t)(k0 + wk) * NCOL + n0 + wc);
    __syncthreads();
    As[akq + 0][arow] = av.x;
    As[akq + 1][arow] = av.y;
    As[akq + 2][arow] = av.z;
    As[akq + 3][arow] = av.w;
    *(float4*)&Ws[wk][wc] = wv;
    __syncthreads();
#pragma unroll
    for (int k = 0; k < BK; ++k) {
      float4 a4 = *(const float4*)&As[k][tr * 4];
      float4 b4 = *(const float4*)&Ws[k][tc * 4];
      float a[4] = {a4.x, a4.y, a4.z, a4.w};
      float b[4] = {b4.x, b4.y, b4.z, b4.w};
#pragma unroll
      for (int i = 0; i < 4; ++i)
#pragma unroll
        for (int j = 0; j < 4; ++j) acc[i][j] += a[i] * b[j];
    }
  }

#pragma unroll
  for (int i = 0; i < 4; ++i) {
    int r = m0 + tr * 4 + i;
    if (r < M) {
      ushort4 u;
      u.x = f2bf(acc[i][0]);
      u.y = f2bf(acc[i][1]);
      u.z = f2bf(acc[i][2]);
      u.w = f2bf(acc[i][3]);
      *(ushort4*)(C + (size_t)r * NCOL + n0 + tc * 4) = u;
    }
  }
}

// ---------------------------------------------------------------------------
// Aggregation: one wave per node, bf16 h input, fp32 out.
// 8-wide unrolled gather: uniform int4x2 src + float4x2 weight loads, then 8
// independent row-gathers in flight (breaks the load-dependency chain).
// ---------------------------------------------------------------------------
template <int COLS>
__global__ __launch_bounds__(256) void aggregate_kernel(
    const unsigned short* __restrict__ h, const int* __restrict__ bucket,
    const float* __restrict__ wbkt, const int* __restrict__ deg,
    const float* __restrict__ dinv, const float* __restrict__ bias,
    float* __restrict__ out, int n) {
  const int wave = threadIdx.x >> 6;
  const int lane = threadIdx.x & 63;
  const int nid = blockIdx.x * 4 + wave;
  if (nid >= n) return;

  const float di = dinv[nid];
  int d = deg[nid];
  if (d > CAP) d = CAP;
  const int* bkt = bucket + (size_t)nid * CAP;
  const float* wb = wbkt + (size_t)nid * CAP;

  if (COLS == 128) {
    const unsigned col = lane * 2;  // two bf16 per lane
    float ax = 0.f, ay = 0.f;
    int p = 0;
    for (; p + 8 <= d; p += 8) {
      int4 s0 = *(const int4*)(bkt + p);
      int4 s1 = *(const int4*)(bkt + p + 4);
      float4 w0 = *(const float4*)(wb + p);
      float4 w1 = *(const float4*)(wb + p + 4);
      unsigned v0 = *(const unsigned*)(h + (size_t)s0.x * 128 + col);
      unsigned v1 = *(const unsigned*)(h + (size_t)s0.y * 128 + col);
      unsigned v2 = *(const unsigned*)(h + (size_t)s0.z * 128 + col);
      unsigned v3 = *(const unsigned*)(h + (size_t)s0.w * 128 + col);
      unsigned v4 = *(const unsigned*)(h + (size_t)s1.x * 128 + col);
      unsigned v5 = *(const unsigned*)(h + (size_t)s1.y * 128 + col);
      unsigned v6 = *(const unsigned*)(h + (size_t)s1.z * 128 + col);
      unsigned v7 = *(const unsigned*)(h + (size_t)s1.w * 128 + col);
      ax += bf_lo(v0) * w0.x + bf_lo(v1) * w0.y + bf_lo(v2) * w0.z + bf_lo(v3) * w0.w;
      ay += bf_hi(v0) * w0.x + bf_hi(v1) * w0.y + bf_hi(v2) * w0.z + bf_hi(v3) * w0.w;
      ax += bf_lo(v4) * w1.x + bf_lo(v5) * w1.y + bf_lo(v6) * w1.z + bf_lo(v7) * w1.w;
      ay += bf_hi(v4) * w1.x + bf_hi(v5) * w1.y + bf_hi(v6) * w1.z + bf_hi(v7) * w1.w;
    }
    for (; p + 4 <= d; p += 4) {
      int4 s0 = *(const int4*)(bkt + p);
      float4 w0 = *(const float4*)(wb + p);
      unsigned v0 = *(const unsigned*)(h + (size_t)s0.x * 128 + col);
      unsigned v1 = *(const unsigned*)(h + (size_t)s0.y * 128 + col);
      unsigned v2 = *(const unsigned*)(h + (size_t)s0.z * 128 + col);
      unsigned v3 = *(const unsigned*)(h + (size_t)s0.w * 128 + col);
      ax += bf_lo(v0) * w0.x + bf_lo(v1) * w0.y + bf_lo(v2) * w0.z + bf_lo(v3) * w0.w;
      ay += bf_hi(v0) * w0.x + bf_hi(v1) * w0.y + bf_hi(v2) * w0.z + bf_hi(v3) * w0.w;
    }
    for (; p < d; ++p) {
      int s = bkt[p];
      float w = wb[p];
      unsigned v = *(const unsigned*)(h + (size_t)s * 128 + col);
      ax += bf_lo(v) * w;
      ay += bf_hi(v) * w;
    }
    float w2 = di * di;
    unsigned v = *(const unsigned*)(h + (size_t)nid * 128 + col);
    ax += bf_lo(v) * w2;
    ay += bf_hi(v) * w2;
    float2 bv = *(const float2*)(bias + col);
    ax = fmaxf(ax + bv.x, 0.f);
    ay = fmaxf(ay + bv.y, 0.f);
    *(float2*)(out + (size_t)nid * 128 + col) = make_float2(ax, ay);
  } else {  // COLS == 64, one bf16 per lane
    float acc = 0.f;
    int p = 0;
    for (; p + 8 <= d; p += 8) {
      int4 s0 = *(const int4*)(bkt + p);
      int4 s1 = *(const int4*)(bkt + p + 4);
      float4 w0 = *(const float4*)(wb + p);
      float4 w1 = *(const float4*)(wb + p + 4);
      unsigned short v0 = h[(size_t)s0.x * 64 + lane];
      unsigned short v1 = h[(size_t)s0.y * 64 + lane];
      unsigned short v2 = h[(size_t)s0.z * 64 + lane];
      unsigned short v3 = h[(size_t)s0.w * 64 + lane];
      unsigned short v4 = h[(size_t)s1.x * 64 + lane];
      unsigned short v5 = h[(size_t)s1.y * 64 + lane];
      unsigned short v6 = h[(size_t)s1.z * 64 + lane];
      unsigned short v7 = h[(size_t)s1.w * 64 + lane];
      acc += bf1(v0) * w0.x + bf1(v1) * w0.y + bf1(v2) * w0.z + bf1(v3) * w0.w;
      acc += bf1(v4) * w1.x + bf1(v5) * w1.y + bf1(v6) * w1.z + bf1(v7) * w1.w;
    }
    for (; p + 4 <= d; p += 4) {
      int4 s0 = *(const int4*)(bkt + p);
      float4 w0 = *(const float4*)(wb + p);
      unsigned short v0 = h[(size_t)s0.x * 64 + lane];
      unsigned short v1 = h[(size_t)s0.y * 64 + lane];
      unsigned short v2 = h[(size_t)s0.z * 64 + lane];
      unsigned short v3 = h[(size_t)s0.w * 64 + lane];
      acc += bf1(v0) * w0.x + bf1(v1) * w0.y + bf1(v2) * w0.z + bf1(v3) * w0.w;
    }
    for (; p < d; ++p) {
      acc += bf1(h[(size_t)bkt[p] * 64 + lane]) * wb[p];
    }
    acc += bf1(h[(size_t)nid * 64 + lane]) * di * di;
    acc = fmaxf(acc + bias[lane], 0.f);
    out[(size_t)nid * 64 + lane] = acc;
  }
}

// ---------------------------------------------------------------------------
extern "C" void kernel_launch(void* const* d_in, const int* in_sizes, int n_in,
                              void* d_out, int out_size, void* d_ws, size_t ws_size,
                              hipStream_t stream) {
  const float* x = (const float*)d_in[0];
  const int* edge = (const int*)d_in[1];
  const float* W1 = (const float*)d_in[2];
  const float* b1 = (const float*)d_in[3];
  const float* W2 = (const float*)d_in[4];
  const float* b2 = (const float*)d_in[5];
  float* out = (float*)d_out;

  const int N = in_sizes[0] / DIN;
  const int E = in_sizes[1] / 2;
  const int* src = edge;
  const int* dst = edge + E;

  char* base = (char*)d_ws;
  size_t off = 0;
  auto carve = [&](size_t bytes) {
    char* p = base + off;
    off += (bytes + 255) & ~(size_t)255;
    return p;
  };
  int* deg = (int*)carve((size_t)N * 4);
  float* dinv = (float*)carve((size_t)N * 4);
  int* bucket = (int*)carve((size_t)N * CAP * 4);
  float* wbkt = (float*)carve((size_t)N * CAP * 4);
  unsigned short* h1 = (unsigned short*)carve((size_t)N * DHID * 2);  // bf16
  float* hb = (float*)carve((size_t)N * DHID * 4);                    // fp32
  unsigned short* h2t = h1;  // alias: h1 dead after aggregate1 (bf16, 64 cols)

  hipMemsetAsync(deg, 0, (size_t)N * 4, stream);

  count_fill_kernel<<<(E + 255) / 256, 256, 0, stream>>>(src, dst, deg, bucket, E);
  dinv_kernel<<<(N + 255) / 256, 256, 0, stream>>>(deg, dinv, N);
  {
    int total = N * CAP;
    weight_fill_kernel<<<(total + 255) / 256, 256, 0, stream>>>(bucket, deg, dinv, wbkt, total);
  }

  // layer 1
  {
    dim3 grid((N + 63) / 64, 2);
    gemm_k128_kernel<DHID><<<grid, 256, 0, stream>>>(x, W1, h1, N);
  }
  aggregate_kernel<DHID><<<(N + 3) / 4, 256, 0, stream>>>(h1, bucket, wbkt, deg, dinv, b1, hb, N);

  // layer 2
  {
    dim3 grid((N + 63) / 64, 1);
    gemm_k128_kernel<DOUT><<<grid, 256, 0, stream>>>(hb, W2, h2t, N);
  }
  aggregate_kernel<DOUT><<<(N + 3) / 4, 256, 0, stream>>>(h2t, bucket, wbkt, deg, dinv, b2, out, N);
}